// Round 1
// baseline (1320.373 us; speedup 1.0000x reference)
//
#include <hip/hip_runtime.h>
#include <math.h>

// Problem constants (from reference setup_inputs)
#define B_    64
#define N_    4096
#define C_    1024
#define K_    8
#define NCHUNK 16
#define TOK_PER (N_ / NCHUNK)   // 256 tokens per chunk
#define EMA_M 0.9f

// ws layout (floats):
//   [0,            B_*NCHUNK*C_)        partial sums   (4 MB)
//   [P_DESC,       P_DESC + B_*C_)      normalized desc (256 KB)
//   then B_ ints: anchor ids
#define P_DESC (B_ * NCHUNK * C_)

// ---------------------------------------------------------------------------
// K1: partial mean over token chunks. grid = (NCHUNK, B_), block = 256.
// Each thread owns 4 channels (float4); loops TOK_PER tokens. Pure streaming.
// ---------------------------------------------------------------------------
__global__ __launch_bounds__(256) void k1_mean_partial(
        const float* __restrict__ x, float* __restrict__ part) {
    const int j = blockIdx.x;      // token chunk
    const int b = blockIdx.y;      // batch
    const int t = threadIdx.x;     // float4 channel index 0..255

    const float4* src = (const float4*)(x + ((size_t)b * N_ + (size_t)j * TOK_PER) * C_) + t;
    float4 acc = make_float4(0.f, 0.f, 0.f, 0.f);
#pragma unroll 8
    for (int n = 0; n < TOK_PER; ++n) {
        float4 v = src[(size_t)n * (C_ / 4)];
        acc.x += v.x; acc.y += v.y; acc.z += v.z; acc.w += v.w;
    }
    ((float4*)(part + (size_t)(b * NCHUNK + j) * C_))[t] = acc;
}

// ---------------------------------------------------------------------------
// K2: finalize desc (mean -> L2 normalize), write desc to ws, compute 8 sims,
// argmax -> ids (int to ws, float to out[0..63]). grid = B_, block = 256.
// ---------------------------------------------------------------------------
__global__ __launch_bounds__(256) void k2_desc_assign(
        const float* __restrict__ part, const float* __restrict__ anchors,
        float* __restrict__ desc, int* __restrict__ ids, float* __restrict__ out) {
    const int b = blockIdx.x;
    const int t = threadIdx.x;
    const int lane = t & 63;
    const int w = t >> 6;

    float4 acc = make_float4(0.f, 0.f, 0.f, 0.f);
#pragma unroll
    for (int j = 0; j < NCHUNK; ++j) {
        float4 v = ((const float4*)(part + (size_t)(b * NCHUNK + j) * C_))[t];
        acc.x += v.x; acc.y += v.y; acc.z += v.z; acc.w += v.w;
    }
    const float invn = 1.0f / (float)N_;
    acc.x *= invn; acc.y *= invn; acc.z *= invn; acc.w *= invn;

    // block reduce sum of squares
    float ss = acc.x * acc.x + acc.y * acc.y + acc.z * acc.z + acc.w * acc.w;
#pragma unroll
    for (int o = 32; o > 0; o >>= 1) ss += __shfl_down(ss, o, 64);
    __shared__ float red[4];
    __shared__ float s_inv;
    if (lane == 0) red[w] = ss;
    __syncthreads();
    if (t == 0) {
        float tot = red[0] + red[1] + red[2] + red[3];
        s_inv = 1.0f / fmaxf(sqrtf(tot), 1e-12f);
    }
    __syncthreads();
    const float iv = s_inv;
    acc.x *= iv; acc.y *= iv; acc.z *= iv; acc.w *= iv;
    ((float4*)(desc + (size_t)b * C_))[t] = acc;

    // 8 anchor dots (anchors are unit-norm already; re-normalizing changes
    // sim by ~1e-7 which cannot flip an argmax on random data)
    float s[K_];
#pragma unroll
    for (int k = 0; k < K_; ++k) {
        float4 a = ((const float4*)(anchors + (size_t)k * C_))[t];
        s[k] = acc.x * a.x + acc.y * a.y + acc.z * a.z + acc.w * a.w;
    }
#pragma unroll
    for (int k = 0; k < K_; ++k) {
#pragma unroll
        for (int o = 32; o > 0; o >>= 1) s[k] += __shfl_down(s[k], o, 64);
    }
    __shared__ float sred[4][K_];
    if (lane == 0) {
#pragma unroll
        for (int k = 0; k < K_; ++k) sred[w][k] = s[k];
    }
    __syncthreads();
    if (t == 0) {
        int best = 0;
        float bv = sred[0][0] + sred[1][0] + sred[2][0] + sred[3][0];
#pragma unroll
        for (int k = 1; k < K_; ++k) {
            float v = sred[0][k] + sred[1][k] + sred[2][k] + sred[3][k];
            if (v > bv) { bv = v; best = k; }   // strict > == first-min of (1-sim)
        }
        ids[b] = best;
        out[b] = (float)best;
    }
}

// ---------------------------------------------------------------------------
// K3: per-anchor sequential EMA chain. grid = K_, block = 64 (one wave).
// Anchor lives in registers (16 ch/lane, coalesced i*64+lane layout).
// Wave-synchronous: no __syncthreads in the chain, only __shfl_xor.
// First assigned sample has m=0 (counts start <1) -> anchor reset to
// normalize(desc); chain depends only on this anchor's samples, in order.
// ---------------------------------------------------------------------------
__global__ __launch_bounds__(64) void k3_ema(
        const float* __restrict__ anchors, const float* __restrict__ counts_in,
        const float* __restrict__ desc, const int* __restrict__ ids,
        float* __restrict__ out) {
    const int k = blockIdx.x;
    const int lane = threadIdx.x;

    const float4* arow = (const float4*)(anchors + (size_t)k * C_);
    float4 a[4];
#pragma unroll
    for (int i = 0; i < 4; ++i) a[i] = arow[i * 64 + lane];

    const float c0 = counts_in[k];
    int cnt = 0;

    for (int b = 0; b < B_; ++b) {
        if (ids[b] != k) continue;   // uniform across the wave
        const float4* drow = (const float4*)(desc + (size_t)b * C_);
        float4 d[4];
#pragma unroll
        for (int i = 0; i < 4; ++i) d[i] = drow[i * 64 + lane];

        const float m = (c0 + (float)cnt < 1.0f) ? 0.0f : EMA_M;
        const float om = 1.0f - m;
        float4 v[4];
        float ss = 0.f;
#pragma unroll
        for (int i = 0; i < 4; ++i) {
            v[i].x = m * a[i].x + om * d[i].x;
            v[i].y = m * a[i].y + om * d[i].y;
            v[i].z = m * a[i].z + om * d[i].z;
            v[i].w = m * a[i].w + om * d[i].w;
            ss += v[i].x * v[i].x + v[i].y * v[i].y + v[i].z * v[i].z + v[i].w * v[i].w;
        }
#pragma unroll
        for (int o = 1; o < 64; o <<= 1) ss += __shfl_xor(ss, o, 64);
        const float iv = 1.0f / fmaxf(sqrtf(ss), 1e-12f);
#pragma unroll
        for (int i = 0; i < 4; ++i) {
            a[i].x = v[i].x * iv; a[i].y = v[i].y * iv;
            a[i].z = v[i].z * iv; a[i].w = v[i].w * iv;
        }
        ++cnt;
    }

    float4* orow = (float4*)(out + 64 + (size_t)k * C_);
#pragma unroll
    for (int i = 0; i < 4; ++i) orow[i * 64 + lane] = a[i];
    if (lane == 0) out[64 + K_ * C_ + k] = c0 + (float)cnt;
}

// ---------------------------------------------------------------------------
extern "C" void kernel_launch(void* const* d_in, const int* in_sizes, int n_in,
                              void* d_out, int out_size, void* d_ws, size_t ws_size,
                              hipStream_t stream) {
    const float* x       = (const float*)d_in[0];   // [64,4096,1024] fp32
    const float* anchors = (const float*)d_in[1];   // [8,1024] fp32 (unit rows)
    const float* counts  = (const float*)d_in[2];   // [8] fp32

    float* out  = (float*)d_out;                    // 64 ids + 8192 anchors + 8 counts
    float* part = (float*)d_ws;                     // [64,16,1024]
    float* desc = part + P_DESC;                    // [64,1024]
    int*   ids  = (int*)(desc + B_ * C_);           // [64]

    k1_mean_partial<<<dim3(NCHUNK, B_), 256, 0, stream>>>(x, part);
    k2_desc_assign<<<B_, 256, 0, stream>>>(part, anchors, desc, ids, out);
    k3_ema<<<K_, 64, 0, stream>>>(anchors, counts, desc, ids, out);
}